// Round 12
// baseline (116.653 us; speedup 1.0000x reference)
//
#include <hip/hip_runtime.h>

#define N_NODES 40000
#define N_EDGES 160000
#define N_FEATS 74
#define DD 1024
#define HD 3072
#define N_GRAPHS 800

// kPre geometry
#define NSLICE 96             // v-slices of 32
#define SLICE_D 32
#define NBLK_LR 57            // ceil((222+1)/4)
// kScanPool geometry
#define SNR 200               // blocks = ranges
#define SRNG 200              // dsts per range (= 4 graphs)

__device__ __forceinline__ float waveReduceSum(float v) {
    #pragma unroll
    for (int off = 32; off > 0; off >>= 1)
        v += __shfl_down(v, off, 64);
    return v;
}
__device__ __forceinline__ float lrelu02(float x) { return x > 0.f ? x : 0.2f * x; }

// ---- K1 kPre ----
// blocks [0,96): slice s (32 dims of flat HD) -> vs = (W1@W2)[slice];
//   wvpar[(h*74+f)*32 + s%32] = W[f, slice] . vs ; bgvpar[s] = bias[slice] . vs
// blocks [96,153): wave-tasks t<222 -> wlr[f*6+{h,3+h}]; t==222 -> c0
__global__ __launch_bounds__(256) void kPre(
    const float* __restrict__ W1, const float* __restrict__ W2,
    const float* __restrict__ b1, const float* __restrict__ b2,
    const float* __restrict__ W, const float* __restrict__ al,
    const float* __restrict__ ar, const float* __restrict__ bias,
    float* __restrict__ wlr, float* __restrict__ c0,
    float* __restrict__ bgvpar, float* __restrict__ wvpar) {
    int wave = threadIdx.x >> 6, lane = threadIdx.x & 63;
    if (blockIdx.x < NSLICE) {
        __shared__ float vs[SLICE_D];
        int s = blockIdx.x;
        int h = s >> 5;                  // 32 slices per head
        int dbase = s * SLICE_D;
        #pragma unroll
        for (int q = 0; q < 8; ++q) {
            int dg = dbase + wave * 8 + q;
            const float* row = W1 + (size_t)dg * DD;
            float acc = 0.f;
            for (int t = lane; t < DD; t += 64) acc += row[t] * W2[t];
            acc = waveReduceSum(acc);
            if (!lane) vs[wave * 8 + q] = acc;
        }
        __syncthreads();
        float vsl = (lane < SLICE_D) ? vs[lane] : 0.f;
        for (int f = wave; f < N_FEATS; f += 4) {
            float p = (lane < SLICE_D) ? W[(size_t)f * HD + dbase + lane] * vsl : 0.f;
            p = waveReduceSum(p);
            if (!lane) wvpar[((size_t)h * N_FEATS + f) * 32 + (s & 31)] = p;
        }
        if (wave == 0) {
            float p = (lane < SLICE_D) ? bias[dbase + lane] * vsl : 0.f;
            p = waveReduceSum(p);
            if (!lane) bgvpar[s] = p;
        }
    } else {
        int t = (blockIdx.x - NSLICE) * 4 + wave;
        if (t < N_FEATS * 3) {
            int f = t / 3, h = t - f * 3;
            const float* rw = W + (size_t)f * HD + h * DD;
            const float* pl = al + h * DD;
            const float* pr = ar + h * DD;
            float aL = 0.f, aR = 0.f;
            for (int tt = lane; tt < DD; tt += 64) {
                float x = rw[tt];
                aL += x * pl[tt]; aR += x * pr[tt];
            }
            aL = waveReduceSum(aL); aR = waveReduceSum(aR);
            if (!lane) { wlr[f * 6 + h] = aL; wlr[f * 6 + 3 + h] = aR; }
        } else if (t == N_FEATS * 3) {
            float acc = 0.f;
            for (int tt = lane; tt < DD; tt += 64) acc += b1[tt] * W2[tt];
            acc = waveReduceSum(acc);
            if (!lane) *c0 = acc + b2[0];
        }
    }
}

// ---- K2 kNode: 2 threads per node (f-range split) ----
__global__ __launch_bounds__(256) void kNode(const float* __restrict__ feats,
                      const float* __restrict__ wlr, const float* __restrict__ wvpar,
                      float4* __restrict__ sn4, float4* __restrict__ er4) {
    __shared__ float lw[N_FEATS * 9];
    int t = threadIdx.x;
    for (int i = t; i < N_FEATS * 6; i += 256)
        lw[(i / 6) * 9 + (i % 6)] = wlr[i];
    for (int j = t; j < N_FEATS * 3; j += 256) {       // j = h*74+f
        int h = j / N_FEATS, f = j - h * N_FEATS;
        const float4* q = (const float4*)(wvpar + (size_t)j * 32);
        float s = 0.f;
        #pragma unroll
        for (int k = 0; k < 8; ++k) {
            float4 p = q[k];
            s += p.x + p.y + p.z + p.w;
        }
        lw[f * 9 + 6 + h] = s;
    }
    __syncthreads();
    int node = blockIdx.x * 128 + (t >> 1);
    if (node >= N_NODES) return;
    int half = t & 1;
    const float* row = feats + (size_t)node * N_FEATS;
    float a0=0,a1=0,a2=0,a3=0,a4=0,a5=0,a6=0,a7=0,a8=0;
    if (half == 0) {
        #pragma unroll
        for (int k = 0; k < 18; ++k) {
            float2 x2 = *(const float2*)(row + k * 2);
            const float* w0 = lw + (k * 2) * 9;
            a0 += x2.x*w0[0]; a1 += x2.x*w0[1]; a2 += x2.x*w0[2];
            a3 += x2.x*w0[3]; a4 += x2.x*w0[4]; a5 += x2.x*w0[5];
            a6 += x2.x*w0[6]; a7 += x2.x*w0[7]; a8 += x2.x*w0[8];
            const float* w1 = w0 + 9;
            a0 += x2.y*w1[0]; a1 += x2.y*w1[1]; a2 += x2.y*w1[2];
            a3 += x2.y*w1[3]; a4 += x2.y*w1[4]; a5 += x2.y*w1[5];
            a6 += x2.y*w1[6]; a7 += x2.y*w1[7]; a8 += x2.y*w1[8];
        }
        float x = row[36];
        const float* wp = lw + 36 * 9;
        a0 += x*wp[0]; a1 += x*wp[1]; a2 += x*wp[2];
        a3 += x*wp[3]; a4 += x*wp[4]; a5 += x*wp[5];
        a6 += x*wp[6]; a7 += x*wp[7]; a8 += x*wp[8];
    } else {
        float x = row[37];
        const float* wp = lw + 37 * 9;
        a0 += x*wp[0]; a1 += x*wp[1]; a2 += x*wp[2];
        a3 += x*wp[3]; a4 += x*wp[4]; a5 += x*wp[5];
        a6 += x*wp[6]; a7 += x*wp[7]; a8 += x*wp[8];
        #pragma unroll
        for (int k = 0; k < 18; ++k) {
            float2 x2 = *(const float2*)(row + 38 + k * 2);
            const float* w0 = lw + (38 + k * 2) * 9;
            a0 += x2.x*w0[0]; a1 += x2.x*w0[1]; a2 += x2.x*w0[2];
            a3 += x2.x*w0[3]; a4 += x2.x*w0[4]; a5 += x2.x*w0[5];
            a6 += x2.x*w0[6]; a7 += x2.x*w0[7]; a8 += x2.x*w0[8];
            const float* w1 = w0 + 9;
            a0 += x2.y*w1[0]; a1 += x2.y*w1[1]; a2 += x2.y*w1[2];
            a3 += x2.y*w1[3]; a4 += x2.y*w1[4]; a5 += x2.y*w1[5];
            a6 += x2.y*w1[6]; a7 += x2.y*w1[7]; a8 += x2.y*w1[8];
        }
    }
    a0 += __shfl_xor(a0, 1, 64); a1 += __shfl_xor(a1, 1, 64);
    a2 += __shfl_xor(a2, 1, 64); a3 += __shfl_xor(a3, 1, 64);
    a4 += __shfl_xor(a4, 1, 64); a5 += __shfl_xor(a5, 1, 64);
    a6 += __shfl_xor(a6, 1, 64); a7 += __shfl_xor(a7, 1, 64);
    a8 += __shfl_xor(a8, 1, 64);
    if (!half) {
        sn4[node * 2]     = make_float4(a0, a1, a2, 0.f);  // el
        sn4[node * 2 + 1] = make_float4(a6, a7, a8, 0.f);  // hv
        er4[node]         = make_float4(a3, a4, a5, 0.f);
    }
}

// dense 64-batch edge processing from a wave's circular queue
__device__ __forceinline__ void processBatch(const int* myq, int wtail, int lane, int nact,
        const int* __restrict__ src, const float4* __restrict__ sn4,
        const float4* __restrict__ er4, int rbase, float* acc) {
    if (lane < nact) {
        int pk = myq[(wtail + lane) & 127];
        int rr = pk & 255;
        int e  = ((unsigned)pk) >> 8;
        int s  = src[e];
        float4 L = sn4[s * 2];
        float4 V = sn4[s * 2 + 1];
        float4 R = er4[rbase + rr];
        float e0 = expf(lrelu02(L.x + R.x));
        float e1 = expf(lrelu02(L.y + R.y));
        float e2 = expf(lrelu02(L.z + R.z));
        float* p = acc + rr * 6;
        atomicAdd(p + 0, e0 * V.x);
        atomicAdd(p + 1, e1 * V.y);
        atomicAdd(p + 2, e2 * V.z);
        atomicAdd(p + 3, e0);
        atomicAdd(p + 4, e1);
        atomicAdd(p + 5, e2);
    }
}

// ---- K3 kScanPool: barrier-free wave-autonomous scan + fused graph pooling ----
// block = range of 200 dsts = 4 graphs. Scans ALL edges (dst L2-resident),
// ballot-compacts matches into per-wave circular queues, drains dense batches.
__global__ __launch_bounds__(256) void kScanPool(const int* __restrict__ src,
        const int* __restrict__ dst, const float4* __restrict__ sn4,
        const float4* __restrict__ er4, const float* __restrict__ bgvpar,
        const float* __restrict__ c0, float* __restrict__ y) {
    __shared__ float acc[SRNG * 6];   // 4.8 KB
    __shared__ int wq[4][128];        // per-wave circular queue, 2 KB
    int tid = threadIdx.x, wave = tid >> 6, lane = tid & 63;
    for (int i = tid; i < SRNG * 6; i += 256) acc[i] = 0.f;
    __syncthreads();
    const int rbase = blockIdx.x * SRNG;
    int* myq = wq[wave];
    int wcnt = 0, wtail = 0;
    const int4* d4 = (const int4*)dst;
    for (int i = tid; i < N_EDGES / 4; i += 256) {
        int4 d = d4[i];
        #pragma unroll
        for (int k = 0; k < 4; ++k) {
            int dd = (k == 0) ? d.x : (k == 1) ? d.y : (k == 2) ? d.z : d.w;
            unsigned rr = (unsigned)(dd - rbase);
            bool match = rr < SRNG;
            unsigned long long m = __ballot(match);
            if (m) {                                 // wave-uniform branch
                if (match) {
                    int off = __popcll(m & ((1ULL << lane) - 1ULL));
                    myq[(wcnt + off) & 127] = ((i * 4 + k) << 8) | (int)rr;
                }
                wcnt += (int)__popcll(m);
                if (wcnt - wtail >= 64) {            // pending <=127 always
                    processBatch(myq, wtail, lane, 64, src, sn4, er4, rbase, acc);
                    wtail += 64;
                }
            }
        }
    }
    int rem = wcnt - wtail;
    if (rem > 0) processBatch(myq, wtail, lane, rem, src, sn4, er4, rbase, acc);
    __syncthreads();
    // fused pooling: wave w -> graph blockIdx*4 + w
    float b = 0.f;
    for (int i = lane; i < NSLICE; i += 64) b += bgvpar[i];
    b = waveReduceSum(b);                            // valid at lane 0
    float cacc = 0.f;
    if (lane < 50) {
        const float* p = acc + (wave * 50 + lane) * 6;
        if (p[3] > 0.f) cacc = p[0] / p[3] + p[1] / p[4] + p[2] / p[5];
    }
    cacc = waveReduceSum(cacc);
    if (!lane) y[blockIdx.x * 4 + wave] = cacc * (1.f / 50.f) + b + c0[0];
}

extern "C" void kernel_launch(void* const* d_in, const int* in_sizes, int n_in,
                              void* d_out, int out_size, void* d_ws, size_t ws_size,
                              hipStream_t stream) {
    const float* feats = (const float*)d_in[0];
    const float* W     = (const float*)d_in[1];
    const float* al    = (const float*)d_in[2];
    const float* ar    = (const float*)d_in[3];
    const float* bias  = (const float*)d_in[4];
    const float* W1    = (const float*)d_in[5];
    const float* b1    = (const float*)d_in[6];
    const float* W2    = (const float*)d_in[7];
    const float* b2    = (const float*)d_in[8];
    const int*   src   = (const int*)d_in[9];
    const int*   dst   = (const int*)d_in[10];

    float* ws     = (float*)d_ws;
    float* wlr    = ws;                    // 444
    float* c0     = ws + 448;              // 1
    float* bgvpar = ws + 512;              // 96
    float* wvpar  = ws + 640;              // 222*32 = 7104
    float* sn     = ws + 8192;             // N*8  (16B aligned)
    float* er     = sn + N_NODES * 8;      // N*4
    float* y      = (float*)d_out;

    hipLaunchKernelGGL(kPre, dim3(NSLICE + NBLK_LR), dim3(256), 0, stream,
                       W1, W2, b1, b2, W, al, ar, bias, wlr, c0, bgvpar, wvpar);
    hipLaunchKernelGGL(kNode, dim3((N_NODES + 127) / 128), dim3(256), 0, stream,
                       feats, wlr, wvpar, (float4*)sn, (float4*)er);
    hipLaunchKernelGGL(kScanPool, dim3(SNR), dim3(256), 0, stream,
                       src, dst, (const float4*)sn, (const float4*)er, bgvpar, c0, y);
}

// Round 15
// 86.179 us; speedup vs baseline: 1.3536x; 1.3536x over previous
//
#include <hip/hip_runtime.h>

#define N_NODES 40000
#define N_EDGES 160000
#define N_FEATS 74
#define DD 1024
#define HD 3072
#define N_GRAPHS 800

// kPre geometry
#define NSLICE 96             // v-slices of 32
#define SLICE_D 32
#define NBLK_LR 57            // ceil((222+1)/4)
// kScanPool geometry
#define SNR 200               // blocks = dst ranges
#define SRNG 200              // dsts per range (= 4 graphs)
#define SNTHR 1024            // 16 waves per block

__device__ __forceinline__ float waveReduceSum(float v) {
    #pragma unroll
    for (int off = 32; off > 0; off >>= 1)
        v += __shfl_down(v, off, 64);
    return v;
}
__device__ __forceinline__ float lrelu02(float x) { return x > 0.f ? x : 0.2f * x; }

// ---- K1 kPre ----
__global__ __launch_bounds__(256) void kPre(
    const float* __restrict__ W1, const float* __restrict__ W2,
    const float* __restrict__ b1, const float* __restrict__ b2,
    const float* __restrict__ W, const float* __restrict__ al,
    const float* __restrict__ ar, const float* __restrict__ bias,
    float* __restrict__ wlr, float* __restrict__ c0,
    float* __restrict__ bgvpar, float* __restrict__ wvpar) {
    int wave = threadIdx.x >> 6, lane = threadIdx.x & 63;
    if (blockIdx.x < NSLICE) {
        __shared__ float vs[SLICE_D];
        int s = blockIdx.x;
        int h = s >> 5;                  // 32 slices per head
        int dbase = s * SLICE_D;
        #pragma unroll
        for (int q = 0; q < 8; ++q) {
            int dg = dbase + wave * 8 + q;
            const float* row = W1 + (size_t)dg * DD;
            float acc = 0.f;
            for (int t = lane; t < DD; t += 64) acc += row[t] * W2[t];
            acc = waveReduceSum(acc);
            if (!lane) vs[wave * 8 + q] = acc;
        }
        __syncthreads();
        float vsl = (lane < SLICE_D) ? vs[lane] : 0.f;
        for (int f = wave; f < N_FEATS; f += 4) {
            float p = (lane < SLICE_D) ? W[(size_t)f * HD + dbase + lane] * vsl : 0.f;
            p = waveReduceSum(p);
            if (!lane) wvpar[((size_t)h * N_FEATS + f) * 32 + (s & 31)] = p;
        }
        if (wave == 0) {
            float p = (lane < SLICE_D) ? bias[dbase + lane] * vsl : 0.f;
            p = waveReduceSum(p);
            if (!lane) bgvpar[s] = p;
        }
    } else {
        int t = (blockIdx.x - NSLICE) * 4 + wave;
        if (t < N_FEATS * 3) {
            int f = t / 3, h = t - f * 3;
            const float* rw = W + (size_t)f * HD + h * DD;
            const float* pl = al + h * DD;
            const float* pr = ar + h * DD;
            float aL = 0.f, aR = 0.f;
            for (int tt = lane; tt < DD; tt += 64) {
                float x = rw[tt];
                aL += x * pl[tt]; aR += x * pr[tt];
            }
            aL = waveReduceSum(aL); aR = waveReduceSum(aR);
            if (!lane) { wlr[f * 6 + h] = aL; wlr[f * 6 + 3 + h] = aR; }
        } else if (t == N_FEATS * 3) {
            float acc = 0.f;
            for (int tt = lane; tt < DD; tt += 64) acc += b1[tt] * W2[tt];
            acc = waveReduceSum(acc);
            if (!lane) *c0 = acc + b2[0];
        }
    }
}

// ---- K2 kNode: 2 threads per node (f-range split) ----
__global__ __launch_bounds__(256) void kNode(const float* __restrict__ feats,
                      const float* __restrict__ wlr, const float* __restrict__ wvpar,
                      float4* __restrict__ sn4, float4* __restrict__ er4) {
    __shared__ float lw[N_FEATS * 9];
    int t = threadIdx.x;
    for (int i = t; i < N_FEATS * 6; i += 256)
        lw[(i / 6) * 9 + (i % 6)] = wlr[i];
    for (int j = t; j < N_FEATS * 3; j += 256) {       // j = h*74+f
        int h = j / N_FEATS, f = j - h * N_FEATS;
        const float4* q = (const float4*)(wvpar + (size_t)j * 32);
        float s = 0.f;
        #pragma unroll
        for (int k = 0; k < 8; ++k) {
            float4 p = q[k];
            s += p.x + p.y + p.z + p.w;
        }
        lw[f * 9 + 6 + h] = s;
    }
    __syncthreads();
    int node = blockIdx.x * 128 + (t >> 1);
    if (node >= N_NODES) return;
    int half = t & 1;
    const float* row = feats + (size_t)node * N_FEATS;
    float a0=0,a1=0,a2=0,a3=0,a4=0,a5=0,a6=0,a7=0,a8=0;
    if (half == 0) {
        #pragma unroll
        for (int k = 0; k < 18; ++k) {
            float2 x2 = *(const float2*)(row + k * 2);
            const float* w0 = lw + (k * 2) * 9;
            a0 += x2.x*w0[0]; a1 += x2.x*w0[1]; a2 += x2.x*w0[2];
            a3 += x2.x*w0[3]; a4 += x2.x*w0[4]; a5 += x2.x*w0[5];
            a6 += x2.x*w0[6]; a7 += x2.x*w0[7]; a8 += x2.x*w0[8];
            const float* w1 = w0 + 9;
            a0 += x2.y*w1[0]; a1 += x2.y*w1[1]; a2 += x2.y*w1[2];
            a3 += x2.y*w1[3]; a4 += x2.y*w1[4]; a5 += x2.y*w1[5];
            a6 += x2.y*w1[6]; a7 += x2.y*w1[7]; a8 += x2.y*w1[8];
        }
        float x = row[36];
        const float* wp = lw + 36 * 9;
        a0 += x*wp[0]; a1 += x*wp[1]; a2 += x*wp[2];
        a3 += x*wp[3]; a4 += x*wp[4]; a5 += x*wp[5];
        a6 += x*wp[6]; a7 += x*wp[7]; a8 += x*wp[8];
    } else {
        float x = row[37];
        const float* wp = lw + 37 * 9;
        a0 += x*wp[0]; a1 += x*wp[1]; a2 += x*wp[2];
        a3 += x*wp[3]; a4 += x*wp[4]; a5 += x*wp[5];
        a6 += x*wp[6]; a7 += x*wp[7]; a8 += x*wp[8];
        #pragma unroll
        for (int k = 0; k < 18; ++k) {
            float2 x2 = *(const float2*)(row + 38 + k * 2);
            const float* w0 = lw + (38 + k * 2) * 9;
            a0 += x2.x*w0[0]; a1 += x2.x*w0[1]; a2 += x2.x*w0[2];
            a3 += x2.x*w0[3]; a4 += x2.x*w0[4]; a5 += x2.x*w0[5];
            a6 += x2.x*w0[6]; a7 += x2.x*w0[7]; a8 += x2.x*w0[8];
            const float* w1 = w0 + 9;
            a0 += x2.y*w1[0]; a1 += x2.y*w1[1]; a2 += x2.y*w1[2];
            a3 += x2.y*w1[3]; a4 += x2.y*w1[4]; a5 += x2.y*w1[5];
            a6 += x2.y*w1[6]; a7 += x2.y*w1[7]; a8 += x2.y*w1[8];
        }
    }
    a0 += __shfl_xor(a0, 1, 64); a1 += __shfl_xor(a1, 1, 64);
    a2 += __shfl_xor(a2, 1, 64); a3 += __shfl_xor(a3, 1, 64);
    a4 += __shfl_xor(a4, 1, 64); a5 += __shfl_xor(a5, 1, 64);
    a6 += __shfl_xor(a6, 1, 64); a7 += __shfl_xor(a7, 1, 64);
    a8 += __shfl_xor(a8, 1, 64);
    if (!half) {
        sn4[node * 2]     = make_float4(a0, a1, a2, 0.f);  // el
        sn4[node * 2 + 1] = make_float4(a6, a7, a8, 0.f);  // hv
        er4[node]         = make_float4(a3, a4, a5, 0.f);
    }
}

// dense batch edge processing from a wave's circular queue
__device__ __forceinline__ void processBatch(const int* myq, int wtail, int lane, int nact,
        const int* __restrict__ src, const float4* __restrict__ sn4,
        const float4* __restrict__ er4, int rbase, float* acc) {
    if (lane < nact) {
        int pk = myq[(wtail + lane) & 127];
        int rr = pk & 255;
        int e  = ((unsigned)pk) >> 8;
        int s  = src[e];
        float4 L = sn4[s * 2];
        float4 V = sn4[s * 2 + 1];
        float4 R = er4[rbase + rr];
        float e0 = expf(lrelu02(L.x + R.x));
        float e1 = expf(lrelu02(L.y + R.y));
        float e2 = expf(lrelu02(L.z + R.z));
        float* p = acc + rr * 6;
        atomicAdd(p + 0, e0 * V.x);
        atomicAdd(p + 1, e1 * V.y);
        atomicAdd(p + 2, e2 * V.z);
        atomicAdd(p + 3, e0);
        atomicAdd(p + 4, e1);
        atomicAdd(p + 5, e2);
    }
}

// ---- K3 kScanPool: 16-wave barrier-free scan + fused graph pooling ----
// block = 200 dsts = 4 graphs; wave w scans edges [w*E/16,(w+1)*E/16) via int4.
// Scan loop is padded to a LANE-UNIFORM trip count (ballot requires it).
__global__ __launch_bounds__(SNTHR) void kScanPool(const int* __restrict__ src,
        const int* __restrict__ dst, const float4* __restrict__ sn4,
        const float4* __restrict__ er4, const float* __restrict__ bgvpar,
        const float* __restrict__ c0, float* __restrict__ y) {
    __shared__ float acc[SRNG * 6];     // 4.8 KB
    __shared__ int wq[16][128];         // per-wave circular queues, 8 KB
    int tid = threadIdx.x, wave = tid >> 6, lane = tid & 63;
    for (int i = tid; i < SRNG * 6; i += SNTHR) acc[i] = 0.f;
    __syncthreads();
    const int rbase = blockIdx.x * SRNG;
    int* myq = wq[wave];
    int wcnt = 0, wtail = 0;
    // wave-private contiguous span: 16 waves x 2500 int4; 40 uniform rounds
    const int SPAN4 = (N_EDGES / 4) / 16;          // 2500
    const int NITER = (SPAN4 + 63) / 64;           // 40 (last round partial)
    const int4* d4 = (const int4*)dst;
    int i0 = wave * SPAN4;
    for (int it = 0; it < NITER; ++it) {
        int j = it * 64 + lane;
        bool valid = j < SPAN4;
        int i = i0 + (valid ? j : 0);
        int4 d = d4[i];                             // clamped addr; masked below
        #pragma unroll
        for (int k = 0; k < 4; ++k) {
            int dd = (k == 0) ? d.x : (k == 1) ? d.y : (k == 2) ? d.z : d.w;
            unsigned rr = (unsigned)(dd - rbase);
            bool match = valid && (rr < SRNG);
            unsigned long long m = __ballot(match);
            if (m) {                                 // wave-uniform
                if (match) {
                    int off = __popcll(m & ((1ULL << lane) - 1ULL));
                    myq[(wcnt + off) & 127] = ((i * 4 + k) << 8) | (int)rr;
                }
                wcnt += (int)__popcll(m);
                if (wcnt - wtail >= 64) {
                    processBatch(myq, wtail, lane, 64, src, sn4, er4, rbase, acc);
                    wtail += 64;
                }
            }
        }
    }
    int rem = wcnt - wtail;
    if (rem > 0) processBatch(myq, wtail, lane, rem, src, sn4, er4, rbase, acc);
    __syncthreads();
    // pooling: waves 0..3 -> graphs blockIdx*4 + wave
    if (wave < 4) {
        float b = 0.f;
        for (int i = lane; i < NSLICE; i += 64) b += bgvpar[i];
        b = waveReduceSum(b);
        float cacc = 0.f;
        if (lane < 50) {
            const float* p = acc + (wave * 50 + lane) * 6;
            if (p[3] > 0.f) cacc = p[0] / p[3] + p[1] / p[4] + p[2] / p[5];
        }
        cacc = waveReduceSum(cacc);
        if (!lane) y[blockIdx.x * 4 + wave] = cacc * (1.f / 50.f) + b + c0[0];
    }
}

extern "C" void kernel_launch(void* const* d_in, const int* in_sizes, int n_in,
                              void* d_out, int out_size, void* d_ws, size_t ws_size,
                              hipStream_t stream) {
    const float* feats = (const float*)d_in[0];
    const float* W     = (const float*)d_in[1];
    const float* al    = (const float*)d_in[2];
    const float* ar    = (const float*)d_in[3];
    const float* bias  = (const float*)d_in[4];
    const float* W1    = (const float*)d_in[5];
    const float* b1    = (const float*)d_in[6];
    const float* W2    = (const float*)d_in[7];
    const float* b2    = (const float*)d_in[8];
    const int*   src   = (const int*)d_in[9];
    const int*   dst   = (const int*)d_in[10];

    float* ws     = (float*)d_ws;
    float* wlr    = ws;                    // 444
    float* c0     = ws + 448;              // 1
    float* bgvpar = ws + 512;              // 96
    float* wvpar  = ws + 640;              // 222*32 = 7104
    float* sn     = ws + 8192;             // N*8  (16B aligned)
    float* er     = sn + N_NODES * 8;      // N*4
    float* y      = (float*)d_out;

    hipLaunchKernelGGL(kPre, dim3(NSLICE + NBLK_LR), dim3(256), 0, stream,
                       W1, W2, b1, b2, W, al, ar, bias, wlr, c0, bgvpar, wvpar);
    hipLaunchKernelGGL(kNode, dim3((N_NODES + 127) / 128), dim3(256), 0, stream,
                       feats, wlr, wvpar, (float4*)sn, (float4*)er);
    hipLaunchKernelGGL(kScanPool, dim3(SNR), dim3(SNTHR), 0, stream,
                       src, dst, (const float4*)sn, (const float4*)er, bgvpar, c0, y);
}

// Round 16
// 62.000 us; speedup vs baseline: 1.8815x; 1.3900x over previous
//
#include <hip/hip_runtime.h>

#define N_NODES 40000
#define N_EDGES 160000
#define N_FEATS 74
#define DD 1024
#define HD 3072
#define N_GRAPHS 800

// kScanPool geometry
#define SNR 200               // blocks = dst ranges
#define SRNG 200              // dsts per range (= 4 graphs)
#define SNTHR 1024            // 16 waves per block

__device__ __forceinline__ float waveReduceSum(float v) {
    #pragma unroll
    for (int off = 32; off > 0; off >>= 1)
        v += __shfl_down(v, off, 64);
    return v;
}
__device__ __forceinline__ float lrelu02(float x) { return x > 0.f ? x : 0.2f * x; }

// ---- K1 kV: one wave-task per dot product ----
// t in [0,3072): v[t] = W1[t,:]·W2 ; t==3072: c0 = b1·W2 + b2
// t in (3072, 3072+222]: u=t-3073 -> f,h: lw9[f*9+h]=W_col·al, lw9[f*9+3+h]=W_col·ar
__global__ __launch_bounds__(256) void kV(
    const float* __restrict__ W1, const float* __restrict__ W2,
    const float* __restrict__ b1, const float* __restrict__ b2,
    const float* __restrict__ W, const float* __restrict__ al,
    const float* __restrict__ ar,
    float* __restrict__ v, float* __restrict__ c0, float* __restrict__ lw9) {
    int wave = threadIdx.x >> 6, lane = threadIdx.x & 63;
    int t = blockIdx.x * 4 + wave;
    if (t < HD) {
        const float* row = W1 + (size_t)t * DD;
        float acc = 0.f;
        for (int i = lane; i < DD; i += 64) acc += row[i] * W2[i];
        acc = waveReduceSum(acc);
        if (!lane) v[t] = acc;
    } else if (t == HD) {
        float acc = 0.f;
        for (int i = lane; i < DD; i += 64) acc += b1[i] * W2[i];
        acc = waveReduceSum(acc);
        if (!lane) c0[0] = acc + b2[0];
    } else if (t < HD + 1 + N_FEATS * 3) {
        int u = t - HD - 1;
        int f = u / 3, h = u - f * 3;
        const float* rw = W + (size_t)f * HD + h * DD;
        const float* pl = al + h * DD;
        const float* pr = ar + h * DD;
        float aL = 0.f, aR = 0.f;
        for (int i = lane; i < DD; i += 64) {
            float x = rw[i];
            aL += x * pl[i]; aR += x * pr[i];
        }
        aL = waveReduceSum(aL); aR = waveReduceSum(aR);
        if (!lane) { lw9[f * 9 + h] = aL; lw9[f * 9 + 3 + h] = aR; }
    }
}

// ---- K2 kWv: u in [0,222): lw9[f*9+6+h] = W_col·v_h ; u==222: bgv = bias·v ----
__global__ __launch_bounds__(256) void kWv(
    const float* __restrict__ W, const float* __restrict__ v,
    const float* __restrict__ bias, float* __restrict__ lw9,
    float* __restrict__ bgv) {
    int wave = threadIdx.x >> 6, lane = threadIdx.x & 63;
    int u = blockIdx.x * 4 + wave;
    if (u < N_FEATS * 3) {
        int f = u / 3, h = u - f * 3;
        const float* rw = W + (size_t)f * HD + h * DD;
        const float* pv = v + h * DD;
        float a = 0.f;
        for (int i = lane; i < DD; i += 64) a += rw[i] * pv[i];
        a = waveReduceSum(a);
        if (!lane) lw9[f * 9 + 6 + h] = a;
    } else if (u == N_FEATS * 3) {
        float a = 0.f;
        for (int i = lane; i < HD; i += 64) a += bias[i] * v[i];
        a = waveReduceSum(a);
        if (!lane) bgv[0] = a;
    }
}

// ---- K3 kNode: 2 threads per node (f-range split); lw9 loaded directly ----
__global__ __launch_bounds__(256) void kNode(const float* __restrict__ feats,
                      const float* __restrict__ lw9,
                      float4* __restrict__ sn4, float4* __restrict__ er4) {
    __shared__ float lw[N_FEATS * 9];
    int t = threadIdx.x;
    for (int i = t; i < N_FEATS * 9; i += 256) lw[i] = lw9[i];
    __syncthreads();
    int node = blockIdx.x * 128 + (t >> 1);
    if (node >= N_NODES) return;
    int half = t & 1;
    const float* row = feats + (size_t)node * N_FEATS;
    float a0=0,a1=0,a2=0,a3=0,a4=0,a5=0,a6=0,a7=0,a8=0;
    if (half == 0) {
        #pragma unroll
        for (int k = 0; k < 18; ++k) {
            float2 x2 = *(const float2*)(row + k * 2);
            const float* w0 = lw + (k * 2) * 9;
            a0 += x2.x*w0[0]; a1 += x2.x*w0[1]; a2 += x2.x*w0[2];
            a3 += x2.x*w0[3]; a4 += x2.x*w0[4]; a5 += x2.x*w0[5];
            a6 += x2.x*w0[6]; a7 += x2.x*w0[7]; a8 += x2.x*w0[8];
            const float* w1 = w0 + 9;
            a0 += x2.y*w1[0]; a1 += x2.y*w1[1]; a2 += x2.y*w1[2];
            a3 += x2.y*w1[3]; a4 += x2.y*w1[4]; a5 += x2.y*w1[5];
            a6 += x2.y*w1[6]; a7 += x2.y*w1[7]; a8 += x2.y*w1[8];
        }
        float x = row[36];
        const float* wp = lw + 36 * 9;
        a0 += x*wp[0]; a1 += x*wp[1]; a2 += x*wp[2];
        a3 += x*wp[3]; a4 += x*wp[4]; a5 += x*wp[5];
        a6 += x*wp[6]; a7 += x*wp[7]; a8 += x*wp[8];
    } else {
        float x = row[37];
        const float* wp = lw + 37 * 9;
        a0 += x*wp[0]; a1 += x*wp[1]; a2 += x*wp[2];
        a3 += x*wp[3]; a4 += x*wp[4]; a5 += x*wp[5];
        a6 += x*wp[6]; a7 += x*wp[7]; a8 += x*wp[8];
        #pragma unroll
        for (int k = 0; k < 18; ++k) {
            float2 x2 = *(const float2*)(row + 38 + k * 2);
            const float* w0 = lw + (38 + k * 2) * 9;
            a0 += x2.x*w0[0]; a1 += x2.x*w0[1]; a2 += x2.x*w0[2];
            a3 += x2.x*w0[3]; a4 += x2.x*w0[4]; a5 += x2.x*w0[5];
            a6 += x2.x*w0[6]; a7 += x2.x*w0[7]; a8 += x2.x*w0[8];
            const float* w1 = w0 + 9;
            a0 += x2.y*w1[0]; a1 += x2.y*w1[1]; a2 += x2.y*w1[2];
            a3 += x2.y*w1[3]; a4 += x2.y*w1[4]; a5 += x2.y*w1[5];
            a6 += x2.y*w1[6]; a7 += x2.y*w1[7]; a8 += x2.y*w1[8];
        }
    }
    a0 += __shfl_xor(a0, 1, 64); a1 += __shfl_xor(a1, 1, 64);
    a2 += __shfl_xor(a2, 1, 64); a3 += __shfl_xor(a3, 1, 64);
    a4 += __shfl_xor(a4, 1, 64); a5 += __shfl_xor(a5, 1, 64);
    a6 += __shfl_xor(a6, 1, 64); a7 += __shfl_xor(a7, 1, 64);
    a8 += __shfl_xor(a8, 1, 64);
    if (!half) {
        sn4[node * 2]     = make_float4(a0, a1, a2, 0.f);  // el
        sn4[node * 2 + 1] = make_float4(a6, a7, a8, 0.f);  // hv
        er4[node]         = make_float4(a3, a4, a5, 0.f);
    }
}

// dense batch edge processing from a wave's circular queue
__device__ __forceinline__ void processBatch(const int* myq, int wtail, int lane, int nact,
        const int* __restrict__ src, const float4* __restrict__ sn4,
        const float4* __restrict__ er4, int rbase, float* acc) {
    if (lane < nact) {
        int pk = myq[(wtail + lane) & 127];
        int rr = pk & 255;
        int e  = ((unsigned)pk) >> 8;
        int s  = src[e];
        float4 L = sn4[s * 2];
        float4 V = sn4[s * 2 + 1];
        float4 R = er4[rbase + rr];
        float e0 = expf(lrelu02(L.x + R.x));
        float e1 = expf(lrelu02(L.y + R.y));
        float e2 = expf(lrelu02(L.z + R.z));
        float* p = acc + rr * 6;
        atomicAdd(p + 0, e0 * V.x);
        atomicAdd(p + 1, e1 * V.y);
        atomicAdd(p + 2, e2 * V.z);
        atomicAdd(p + 3, e0);
        atomicAdd(p + 4, e1);
        atomicAdd(p + 5, e2);
    }
}

// ---- K4 kScanPool: 16-wave barrier-free scan + fused graph pooling ----
__global__ __launch_bounds__(SNTHR) void kScanPool(const int* __restrict__ src,
        const int* __restrict__ dst, const float4* __restrict__ sn4,
        const float4* __restrict__ er4, const float* __restrict__ bgv,
        const float* __restrict__ c0, float* __restrict__ y) {
    __shared__ float acc[SRNG * 6];     // 4.8 KB
    __shared__ int wq[16][128];         // per-wave circular queues, 8 KB
    int tid = threadIdx.x, wave = tid >> 6, lane = tid & 63;
    for (int i = tid; i < SRNG * 6; i += SNTHR) acc[i] = 0.f;
    __syncthreads();
    const int rbase = blockIdx.x * SRNG;
    int* myq = wq[wave];
    int wcnt = 0, wtail = 0;
    const int SPAN4 = (N_EDGES / 4) / 16;          // 2500
    const int NITER = (SPAN4 + 63) / 64;           // 40 uniform rounds
    const int4* d4 = (const int4*)dst;
    int i0 = wave * SPAN4;
    for (int it = 0; it < NITER; ++it) {
        int j = it * 64 + lane;
        bool valid = j < SPAN4;
        int i = i0 + (valid ? j : 0);
        int4 d = d4[i];
        #pragma unroll
        for (int k = 0; k < 4; ++k) {
            int dd = (k == 0) ? d.x : (k == 1) ? d.y : (k == 2) ? d.z : d.w;
            unsigned rr = (unsigned)(dd - rbase);
            bool match = valid && (rr < SRNG);
            unsigned long long m = __ballot(match);
            if (m) {
                if (match) {
                    int off = __popcll(m & ((1ULL << lane) - 1ULL));
                    myq[(wcnt + off) & 127] = ((i * 4 + k) << 8) | (int)rr;
                }
                wcnt += (int)__popcll(m);
                if (wcnt - wtail >= 64) {
                    processBatch(myq, wtail, lane, 64, src, sn4, er4, rbase, acc);
                    wtail += 64;
                }
            }
        }
    }
    int rem = wcnt - wtail;
    if (rem > 0) processBatch(myq, wtail, lane, rem, src, sn4, er4, rbase, acc);
    __syncthreads();
    if (wave < 4) {
        float cacc = 0.f;
        if (lane < 50) {
            const float* p = acc + (wave * 50 + lane) * 6;
            if (p[3] > 0.f) cacc = p[0] / p[3] + p[1] / p[4] + p[2] / p[5];
        }
        cacc = waveReduceSum(cacc);
        if (!lane) y[blockIdx.x * 4 + wave] = cacc * (1.f / 50.f) + bgv[0] + c0[0];
    }
}

extern "C" void kernel_launch(void* const* d_in, const int* in_sizes, int n_in,
                              void* d_out, int out_size, void* d_ws, size_t ws_size,
                              hipStream_t stream) {
    const float* feats = (const float*)d_in[0];
    const float* W     = (const float*)d_in[1];
    const float* al    = (const float*)d_in[2];
    const float* ar    = (const float*)d_in[3];
    const float* bias  = (const float*)d_in[4];
    const float* W1    = (const float*)d_in[5];
    const float* b1    = (const float*)d_in[6];
    const float* W2    = (const float*)d_in[7];
    const float* b2    = (const float*)d_in[8];
    const int*   src   = (const int*)d_in[9];
    const int*   dst   = (const int*)d_in[10];

    float* ws  = (float*)d_ws;
    float* v   = ws;                      // 3072
    float* lw9 = ws + 3072;               // 666 (pad to 672)
    float* c0  = ws + 3776;               // 1
    float* bgv = ws + 3777;               // 1
    float* sn  = ws + 4096;               // N*8 (16B aligned)
    float* er  = sn + N_NODES * 8;        // N*4
    float* y   = (float*)d_out;

    hipLaunchKernelGGL(kV, dim3((HD + 1 + N_FEATS * 3 + 3) / 4), dim3(256), 0, stream,
                       W1, W2, b1, b2, W, al, ar, v, c0, lw9);
    hipLaunchKernelGGL(kWv, dim3((N_FEATS * 3 + 1 + 3) / 4), dim3(256), 0, stream,
                       W, v, bias, lw9, bgv);
    hipLaunchKernelGGL(kNode, dim3((N_NODES + 127) / 128), dim3(256), 0, stream,
                       feats, lw9, (float4*)sn, (float4*)er);
    hipLaunchKernelGGL(kScanPool, dim3(SNR), dim3(SNTHR), 0, stream,
                       src, dst, (const float4*)sn, (const float4*)er, bgv, c0, y);
}